// Round 2
// baseline (151.841 us; speedup 1.0000x reference)
//
#include <hip/hip_runtime.h>

// Problem constants: T=8192 frames, D=256, P=64 phones, K=128 centers/phone
#define T_FRAMES 8192
#define D_DIM    256
#define P_PHONES 64
#define K_CENT   128
#define NSLICE   8      // K split into 8 slices of 16 centers
#define SLICE_C  16
#define TILE_M   64     // frames per tile == wavefront size
#define MAX_TILES 192   // sum ceil(c_p/64) <= 191
#define MAX_UNITS (MAX_TILES * NSLICE)   // 1536

// ws byte layout
#define WS_NUNITS   0        // int
#define WS_NORMS    16       // float[8192]  (32 KB)
#define WS_FIDX     32784    // int[8192]    (32 KB)
#define WS_DESC     65552    // int4[1536]   (24 KB)
#define WS_MINKEY   90128    // u64[8192]    (64 KB)  total ~152 KB

// ---------------- K1: center norms ----------------
__global__ __launch_bounds__(256) void qr_norms_kernel(const float* __restrict__ centers,
                                                       float* __restrict__ norms) {
    const int gwave = (blockIdx.x * blockDim.x + threadIdx.x) >> 6;
    const int lane  = threadIdx.x & 63;
    const float4* c4 = (const float4*)(centers + (size_t)gwave * D_DIM);
    float4 cv = c4[lane];
    float s = cv.x * cv.x + cv.y * cv.y + cv.z * cv.z + cv.w * cv.w;
#pragma unroll
    for (int off = 32; off; off >>= 1) s += __shfl_xor(s, off, 64);
    if (lane == 0) norms[gwave] = s;
}

// ---------------- K2: bucket frames by phone, build wave-unit descriptors ----------------
// Single block, 1024 threads. Also initializes minkey to all-ones.
__global__ __launch_bounds__(1024) void qr_bucket_kernel(const int* __restrict__ phones,
                                                         int* __restrict__ ws_n,
                                                         int* __restrict__ fidx,
                                                         int4* __restrict__ desc,
                                                         unsigned long long* __restrict__ minkey) {
    __shared__ int hist[P_PHONES];
    __shared__ int basep[P_PHONES];
    __shared__ int offp[P_PHONES];
    const int tid = threadIdx.x;

    if (tid < P_PHONES) hist[tid] = 0;
    // init minkey (ws is poisoned 0xAA before every call)
    for (int i = tid; i < T_FRAMES; i += 1024) minkey[i] = 0xFFFFFFFFFFFFFFFFull;
    __syncthreads();

    for (int i = tid; i < T_FRAMES; i += 1024) atomicAdd(&hist[phones[i]], 1);
    __syncthreads();

    if (tid < P_PHONES) {   // wave 0 only: scans + descriptor emit
        const int c = hist[tid];
        // inclusive scan of counts over 64 lanes
        int x = c;
#pragma unroll
        for (int off = 1; off < 64; off <<= 1) {
            int y = __shfl_up(x, off, 64);
            if (tid >= off) x += y;
        }
        const int fbase = x - c;      // exclusive prefix = bucket start
        basep[tid] = fbase;
        offp[tid]  = fbase;
        // tile counts and their scan
        const int nt = (c + TILE_M - 1) / TILE_M;
        int tx = nt;
#pragma unroll
        for (int off = 1; off < 64; off <<= 1) {
            int y = __shfl_up(tx, off, 64);
            if (tid >= off) tx += y;
        }
        const int tb = tx - nt;       // exclusive tile base
        for (int j = 0; j < nt; ++j) {
            const int fs = fbase + j * TILE_M;
            const int fc = min(TILE_M, c - j * TILE_M);
#pragma unroll
            for (int s = 0; s < NSLICE; ++s)
                desc[(tb + j) * NSLICE + s] = make_int4(tid, fs, fc, s);
        }
        if (tid == 63) ws_n[0] = tx * NSLICE;   // total units
    }
    __syncthreads();

    for (int i = tid; i < T_FRAMES; i += 1024) {
        const int p = phones[i];
        const int pos = atomicAdd(&offp[p], 1);
        fidx[pos] = i;
    }
}

// ---------------- K3: per-(tile,slice) distance + slice argmin ----------------
// wave-unit = 64 frames (lane=frame) x 16 centers. Centers via scalar loads
// (wave-uniform addresses -> s_load, B operand rides the SGPR slot of v_fma).
__global__ __launch_bounds__(256) void qr_slice_kernel(const float* __restrict__ h,
                                                       const float* __restrict__ centers,
                                                       const float* __restrict__ norms,
                                                       const int* __restrict__ ws_n,
                                                       const int* __restrict__ fidx,
                                                       const int4* __restrict__ desc,
                                                       unsigned long long* __restrict__ minkey) {
    const int wv = __builtin_amdgcn_readfirstlane((int)((blockIdx.x << 2) | (threadIdx.x >> 6)));
    const int n_units = ws_n[0];
    if (wv >= n_units) return;

    const int4 dsc  = desc[wv];
    const int p = dsc.x, fstart = dsc.y, fcnt = dsc.z, s = dsc.w;
    const int lane = threadIdx.x & 63;
    const int fl   = lane < fcnt ? lane : fcnt - 1;   // clamp (dup last frame, write-guarded)
    const int fi   = fidx[fstart + fl];

    const float4* h4    = (const float4*)(h + (size_t)fi * D_DIM);
    const float*  cbase = centers + ((size_t)p * K_CENT + s * SLICE_C) * D_DIM;

    float acc[SLICE_C];
#pragma unroll
    for (int c = 0; c < SLICE_C; ++c) acc[c] = 0.0f;

    for (int d0 = 0; d0 < D_DIM / 16; ++d0) {         // 16 dims per step
        const float4 a0 = h4[d0 * 4 + 0];
        const float4 a1 = h4[d0 * 4 + 1];
        const float4 a2 = h4[d0 * 4 + 2];
        const float4 a3 = h4[d0 * 4 + 3];
        const float* cp = cbase + d0 * 16;
#pragma unroll
        for (int c = 0; c < SLICE_C; ++c) {
            const float* cr = cp + (size_t)c * D_DIM;  // wave-uniform -> s_load_dwordx16
            float t0 = a0.x * cr[0]  + a0.y * cr[1]  + a0.z * cr[2]  + a0.w * cr[3];
            float t1 = a1.x * cr[4]  + a1.y * cr[5]  + a1.z * cr[6]  + a1.w * cr[7];
            float t2 = a2.x * cr[8]  + a2.y * cr[9]  + a2.z * cr[10] + a2.w * cr[11];
            float t3 = a3.x * cr[12] + a3.y * cr[13] + a3.z * cr[14] + a3.w * cr[15];
            acc[c] += (t0 + t1) + (t2 + t3);
        }
    }

    // slice-local argmin (ascending c + strict '<' => lowest k on ties)
    const float* nb = norms + p * K_CENT + s * SLICE_C;
    float best = 3.0e38f; int bk = 0;
#pragma unroll
    for (int c = 0; c < SLICE_C; ++c) {
        const float d2 = nb[c] - 2.0f * acc[c];
        if (d2 < best) { best = d2; bk = c; }
    }

    if (lane < fcnt) {
        unsigned ub = __float_as_uint(best);
        ub = (ub & 0x80000000u) ? ~ub : (ub | 0x80000000u);   // monotone float->uint
        const unsigned long long key =
            ((unsigned long long)ub << 32) | (unsigned)(s * SLICE_C + bk);
        atomicMin(minkey + fi, key);   // lowest d2, then lowest k: matches jnp.argmin
    }
}

// ---------------- K4: decode winner, copy center row ----------------
__global__ __launch_bounds__(256) void qr_emit_kernel(const float* __restrict__ centers,
                                                      const int* __restrict__ phones,
                                                      const unsigned long long* __restrict__ minkey,
                                                      float* __restrict__ out) {
    const int wave = threadIdx.x >> 6;
    const int lane = threadIdx.x & 63;
    const int t    = blockIdx.x * 4 + wave;
    const unsigned long long key = minkey[t];
    const int k = (int)(key & (K_CENT - 1));
    const int p = phones[t];
    const float4* c4 = (const float4*)(centers + ((size_t)p * K_CENT + k) * D_DIM);
    ((float4*)(out + (size_t)t * D_DIM))[lane] = c4[lane];
}

extern "C" void kernel_launch(void* const* d_in, const int* in_sizes, int n_in,
                              void* d_out, int out_size, void* d_ws, size_t ws_size,
                              hipStream_t stream) {
    const float* h       = (const float*)d_in[0];
    const float* centers = (const float*)d_in[1];
    const int*   phones  = (const int*)d_in[2];
    float*       out     = (float*)d_out;

    char* ws = (char*)d_ws;
    int*                ws_n   = (int*)(ws + WS_NUNITS);
    float*              norms  = (float*)(ws + WS_NORMS);
    int*                fidx   = (int*)(ws + WS_FIDX);
    int4*               desc   = (int4*)(ws + WS_DESC);
    unsigned long long* minkey = (unsigned long long*)(ws + WS_MINKEY);

    qr_norms_kernel<<<(P_PHONES * K_CENT) / 4, 256, 0, stream>>>(centers, norms);
    qr_bucket_kernel<<<1, 1024, 0, stream>>>(phones, ws_n, fidx, desc, minkey);
    qr_slice_kernel<<<MAX_UNITS / 4, 256, 0, stream>>>(h, centers, norms, ws_n, fidx, desc, minkey);
    qr_emit_kernel<<<T_FRAMES / 4, 256, 0, stream>>>(centers, phones, minkey, out);
}

// Round 3
// 131.312 us; speedup vs baseline: 1.1563x; 1.1563x over previous
//
#include <hip/hip_runtime.h>

// T=8192 frames, D=256, P=64 phones, K=128 centers/phone
#define T_FRAMES 8192
#define D_DIM    256
#define P_PHONES 64
#define K_CENT   128
#define TILE_F   16          // frames per tile (= per block)
#define MAX_TILES 576        // sum ceil(c_p/16) <= 576

// ws byte layout
#define WS_NUNITS 0              // int
#define WS_NORMS  16             // float[8192]   (32 KB)
#define WS_FIDX   (16 + 32768)   // int[8192]     (32 KB)
#define WS_DESC   (16 + 65536)   // int4[576]     (9 KB)

// ---------------- K1: prep = center norms (blocks 1..512) + bucketing (block 0) ----
__global__ __launch_bounds__(1024) void qr_prep_kernel(const float* __restrict__ centers,
                                                       const int* __restrict__ phones,
                                                       float* __restrict__ norms,
                                                       int* __restrict__ ws_n,
                                                       int* __restrict__ fidx,
                                                       int4* __restrict__ desc) {
    const int b   = blockIdx.x;
    const int tid = threadIdx.x;

    if (b > 0) {
        // norms: 16 waves/block, one center per wave. blocks 1..512 -> 8192 centers
        const int gwave = (b - 1) * 16 + (tid >> 6);
        const int lane  = tid & 63;
        const float4 cv = ((const float4*)(centers + (size_t)gwave * D_DIM))[lane];
        float s = cv.x * cv.x + cv.y * cv.y + cv.z * cv.z + cv.w * cv.w;
#pragma unroll
        for (int off = 32; off; off >>= 1) s += __shfl_xor(s, off, 64);
        if (lane == 0) norms[gwave] = s;
        return;
    }

    // block 0: counting-sort frames by phone + tile descriptors
    __shared__ int hist[P_PHONES];
    __shared__ int offp[P_PHONES];
    if (tid < P_PHONES) hist[tid] = 0;
    __syncthreads();
    for (int i = tid; i < T_FRAMES; i += 1024) atomicAdd(&hist[phones[i]], 1);
    __syncthreads();

    if (tid < P_PHONES) {   // wave 0: scans + descriptor emit (lane = phone)
        const int c = hist[tid];
        int x = c;
#pragma unroll
        for (int off = 1; off < 64; off <<= 1) {
            int y = __shfl_up(x, off, 64);
            if (tid >= off) x += y;
        }
        const int fbase = x - c;
        offp[tid] = fbase;
        const int nt = (c + TILE_F - 1) / TILE_F;
        int tx = nt;
#pragma unroll
        for (int off = 1; off < 64; off <<= 1) {
            int y = __shfl_up(tx, off, 64);
            if (tid >= off) tx += y;
        }
        const int tb = tx - nt;
        for (int j = 0; j < nt; ++j)
            desc[tb + j] = make_int4(tid, fbase + j * TILE_F, min(TILE_F, c - j * TILE_F), 0);
        if (tid == 63) ws_n[0] = tx;
    }
    __syncthreads();

    for (int i = tid; i < T_FRAMES; i += 1024) {
        const int p = phones[i];
        fidx[atomicAdd(&offp[p], 1)] = i;   // intra-bucket order irrelevant (per-frame results)
    }
}

// ---------------- K2: main. block = 16 frames x 128 centers; wave w = centers [16w,16w+16).
// lane = (f, g): f = frame 0..15, g = dim-quarter 0..3 (64 dims each).
// No scalar loads, no global atomics; block writes output rows directly.
__global__ __launch_bounds__(512, 4) void qr_main_kernel(const float* __restrict__ h,
                                                         const float* __restrict__ centers,
                                                         const float* __restrict__ norms,
                                                         const int* __restrict__ ws_n,
                                                         const int* __restrict__ fidx,
                                                         const int4* __restrict__ desc,
                                                         float* __restrict__ out) {
    const int b = blockIdx.x;
    if (b >= ws_n[0]) return;
    const int4 dsc = desc[b];
    const int p = dsc.x, fstart = dsc.y, fcnt = dsc.z;

    const int tid  = threadIdx.x;
    const int wave = tid >> 6;       // 0..7 -> center slice
    const int lane = tid & 63;
    const int f    = lane & 15;
    const int g    = lane >> 4;

    const int fl = f < fcnt ? f : fcnt - 1;   // clamp: duplicate last frame, write-guarded
    const int fi = fidx[fstart + fl];

    const float4* h4    = (const float4*)(h + (size_t)fi * D_DIM + g * 64);
    const float*  cbase = centers + ((size_t)p * K_CENT + wave * 16) * D_DIM + g * 64;
    const float*  nb    = norms + p * K_CENT + wave * 16;

    float acc[16];
#pragma unroll
    for (int c = 0; c < 16; ++c) acc[c] = 0.0f;

#pragma unroll
    for (int j = 0; j < 16; ++j) {            // 4 dims per j, 64 dims per lane
        const float4 hv = h4[j];
#pragma unroll
        for (int c = 0; c < 16; ++c) {
            const float4 cv = ((const float4*)(cbase + (size_t)c * D_DIM))[j];
            acc[c] = fmaf(hv.w, cv.w, fmaf(hv.z, cv.z, fmaf(hv.y, cv.y, fmaf(hv.x, cv.x, acc[c]))));
        }
    }

    // combine the 4 dim-quarters; result bit-identical across the 4 g-lanes
    float best = 3.0e38f; int bk = 0;
#pragma unroll
    for (int c = 0; c < 16; ++c) {
        float s = acc[c];
        s += __shfl_xor(s, 16, 64);
        s += __shfl_xor(s, 32, 64);
        const float d2 = nb[c] - 2.0f * s;
        if (d2 < best) { best = d2; bk = c; }   // strict '<': lowest c on ties
    }

    __shared__ unsigned long long keys[8][TILE_F];
    __shared__ int widx[TILE_F];
    unsigned ub = __float_as_uint(best);
    ub = (ub & 0x80000000u) ? ~ub : (ub | 0x80000000u);   // monotone float->uint
    if (g == 0)
        keys[wave][f] = ((unsigned long long)ub << 32) | (unsigned)(wave * 16 + bk);
    __syncthreads();

    if (tid < TILE_F) {   // per-frame min over 8 slices; key embeds k -> lowest k on ties
        unsigned long long m = keys[0][tid];
#pragma unroll
        for (int w = 1; w < 8; ++w) m = min(m, keys[w][tid]);
        widx[tid] = (int)(m & 0xFFu);
    }
    __syncthreads();

    // copy winning rows: 32 threads per frame, 64 float4 per row
    const int f2 = tid >> 5;
    const int j2 = tid & 31;
    if (f2 < fcnt) {
        const int fo = fidx[fstart + f2];
        const float4* src = (const float4*)(centers + ((size_t)p * K_CENT + widx[f2]) * D_DIM);
        float4* dst = (float4*)(out + (size_t)fo * D_DIM);
        dst[j2]      = src[j2];
        dst[j2 + 32] = src[j2 + 32];
    }
}

extern "C" void kernel_launch(void* const* d_in, const int* in_sizes, int n_in,
                              void* d_out, int out_size, void* d_ws, size_t ws_size,
                              hipStream_t stream) {
    const float* h       = (const float*)d_in[0];
    const float* centers = (const float*)d_in[1];
    const int*   phones  = (const int*)d_in[2];
    float*       out     = (float*)d_out;

    char* ws = (char*)d_ws;
    int*   ws_n  = (int*)(ws + WS_NUNITS);
    float* norms = (float*)(ws + WS_NORMS);
    int*   fidx  = (int*)(ws + WS_FIDX);
    int4*  desc  = (int4*)(ws + WS_DESC);

    // block 0: bucketing; blocks 1..512: norms (16 centers each)
    qr_prep_kernel<<<513, 1024, 0, stream>>>(centers, phones, norms, ws_n, fidx, desc);
    qr_main_kernel<<<MAX_TILES, 512, 0, stream>>>(h, centers, norms, ws_n, fidx, desc, out);
}